// Round 1
// baseline (411.861 us; speedup 1.0000x reference)
//
#include <hip/hip_runtime.h>

// VQ-VAE eval forward, MI355X — R8: split the 256 MB one-hot encodings write.
// R7 streamed enc as conditional 8-B nontemporal stores inside the mega kernel
// (Phase D). enc's base offset (out + 4194306 floats) is only 8-B aligned, so
// the fused writer is capped at floatx2 width (512 B/wave/instr) — roughly
// half the proven 16 B/lane store width, and it runs from only 8 waves/CU
// after the Phase-C barrier. R8 instead:
//   - zero-fills the enc region with 16-B-aligned float4 nontemporal stores
//     at full grid occupancy (folded into the init kernel; head/tail f2 fix
//     the 8-B misalignment — impossible for the one-hot writer, trivial for
//     a pure zero fill),
//   - scatters the 65536 ones (0.25 MB) from mega's Phase-C reducer lanes,
//   - deletes Phase D.
// inputs:  d_in[0] = inputs  fp32 [64,64,32,32] NCHW  (4,194,304)
//          d_in[1] = emb     fp32 [1024,64]           (65,536)
// outputs in d_out (fp32, flat): loss | quantized NCHW (4194304) |
//          perplexity | encodings [65536,1024] (256 MB)

#define NROWS 65536
#define DIM   64
#define KCB   1024

typedef __attribute__((ext_vector_type(8))) short  short8;
typedef __attribute__((ext_vector_type(4))) float  floatx4;
typedef __attribute__((ext_vector_type(2))) float  floatx2;

__device__ inline unsigned short f2bf(float f) {
    unsigned u = __float_as_uint(f);
    u = u + 0x7fffu + ((u >> 16) & 1u);      // round-to-nearest-even
    return (unsigned short)(u >> 16);
}
__device__ inline float bf2f(unsigned short h) {
    return __uint_as_float(((unsigned)h) << 16);
}

// ---- init+zero: all 2048 blocks zero-fill the enc region (256 MB) with
// aligned float4 nt stores; blocks 0..3 additionally prep the codebook:
// se[k], hist=0, scalars=0, e -> B-fragment-ordered bf16 hi/lo.
// B-frag layout (16x16x32): elem (ct,kt,lane,j) = emb[code=ct*16+(lane&15)]
//                           [dim=kt*32+(lane>>4)*8+j]
__global__ __launch_bounds__(256) void vq_initzero_kernel(
    const float* __restrict__ emb, float* __restrict__ se,
    int* __restrict__ hist, float* __restrict__ lossacc, float* __restrict__ sumx2,
    short8* __restrict__ ebh, short8* __restrict__ ebl,
    float* __restrict__ enc)
{
    const int tid = threadIdx.x;
    const unsigned gid = blockIdx.x * 256u + (unsigned)tid;

    // ---- enc zero fill: [enc, enc+67108864) floats. Base is 8-B aligned
    // only; enc+2 is 16-B aligned. bulk = 16,777,215 float4, head/tail f2.
    {
        floatx4* e4 = (floatx4*)(enc + 2);
        const floatx4 z4 = {0.f, 0.f, 0.f, 0.f};
        for (unsigned i = gid; i < 16777215u; i += 524288u)
            __builtin_nontemporal_store(z4, &e4[i]);
        if (gid == 0) {
            enc[0] = 0.f; enc[1] = 0.f;
            enc[67108862] = 0.f; enc[67108863] = 0.f;
        }
    }

    if (blockIdx.x >= 4) return;

    // ---- codebook prep (blocks 0..3 only) ----
    const int code = blockIdx.x * 256 + tid;   // 0..1023
    const float* e = emb + (code << 6);
    float s = 0.f;
    float v[DIM];
#pragma unroll
    for (int d = 0; d < DIM; ++d) { v[d] = e[d]; s = fmaf(v[d], v[d], s); }
    se[code] = s;
    hist[code] = 0;
    if (code == 0) { lossacc[0] = 0.f; sumx2[0] = 0.f; }

    const int ct = code >> 4;
#pragma unroll
    for (int jg = 0; jg < 8; ++jg) {                   // dims jg*8 .. jg*8+7
        const int kt   = jg >> 2;
        const int lane = (code & 15) + 16 * (jg & 3);
        short8 h8, l8;
#pragma unroll
        for (int j = 0; j < 8; ++j) {
            float x = v[jg * 8 + j];
            unsigned short h = f2bf(x);
            h8[j] = (short)h;
            l8[j] = (short)f2bf(x - bf2f(h));
        }
        ebh[(ct * 2 + kt) * 64 + lane] = h8;
        ebl[(ct * 2 + kt) * 64 + lane] = l8;
    }
}

// ---- mega: block = 128 rows. Phase A: x load + bf16-split -> LDS A-frags.
//      Phase B: MFMA argmin over all 1024 codes (B-frags double-buffered from
//      global). Phase C: idx/hist/loss + scatter the one-hot 1.0 per row.
__global__ __launch_bounds__(256) void vq_mega_kernel(
    const float* __restrict__ inp, const short8* __restrict__ ebh,
    const short8* __restrict__ ebl, const float* __restrict__ se,
    int* __restrict__ idxout, int* __restrict__ hist,
    float* __restrict__ lossacc, float* __restrict__ sumx2,
    float* __restrict__ enc)
{
    __shared__ short8 fragH[1024];   // [s16_loc(8)][kt(2)][lane(64)], 16 KB
    __shared__ short8 fragL[1024];   // 16 KB

    const int tid  = threadIdx.x;
    const int rblk = blockIdx.x << 7;        // first row of this block
    const int n    = rblk >> 10;             // 128 | 1024 -> single n per block
    const int hw0  = rblk & 1023;

    // ---- Phase A ----
    {
        const int r_loc = tid & 127;
        const int half  = tid >> 7;          // dims half*32 .. +31
        const float* base = inp + n * 65536 + hw0 + r_loc;
        float v[32];
        float s2 = 0.f;
#pragma unroll
        for (int j = 0; j < 32; ++j) {
            v[j] = base[(half * 32 + j) << 10];   // 256 B coalesced per instr
            s2 = fmaf(v[j], v[j], s2);
        }
        const int s16 = r_loc >> 4;
#pragma unroll
        for (int jg2 = 0; jg2 < 4; ++jg2) {       // jg = half*4 + jg2
            short8 h8, l8;
#pragma unroll
            for (int jj = 0; jj < 8; ++jj) {
                float x = v[jg2 * 8 + jj];
                unsigned short h = f2bf(x);
                h8[jj] = (short)h;
                l8[jj] = (short)f2bf(x - bf2f(h));
            }
            // kt = jg>>2 = half; lane = (row&15) + 16*(jg&3), jg&3 = jg2
            int fi = (s16 * 2 + half) * 64 + (r_loc & 15) + (jg2 << 4);
            fragH[fi] = h8;
            fragL[fi] = l8;
        }
#pragma unroll
        for (int m = 1; m <= 32; m <<= 1) s2 += __shfl_xor(s2, m, 64);
        if ((tid & 63) == 0) atomicAdd(sumx2, s2);
    }
    __syncthreads();

    // ---- Phase B: MFMA argmin ----
    const int lane = tid & 63;
    const int wid  = tid >> 6;

    short8 ah[2][2], al[2][2];
#pragma unroll
    for (int s = 0; s < 2; ++s)
#pragma unroll
        for (int kt = 0; kt < 2; ++kt) {
            int fi = ((wid * 2 + s) * 2 + kt) * 64 + lane;
            ah[s][kt] = fragH[fi];
            al[s][kt] = fragL[fi];
        }

    float minv[2][4]; int mini[2][4];
#pragma unroll
    for (int s = 0; s < 2; ++s)
#pragma unroll
        for (int r = 0; r < 4; ++r) { minv[s][r] = 3.0e38f; mini[s][r] = 0; }

    const int cl = lane & 15;
    short8 b0h = ebh[lane], b0l = ebl[lane];
    short8 b1h = ebh[64 + lane], b1l = ebl[64 + lane];

    for (int ct = 0; ct < 64; ++ct) {
        short8 ch0 = b0h, cB0 = b0l, ch1 = b1h, cB1 = b1l;
        if (ct < 63) {                         // double-buffer next B-frags
            b0h = ebh[(ct + 1) * 128 + lane];
            b0l = ebl[(ct + 1) * 128 + lane];
            b1h = ebh[(ct + 1) * 128 + 64 + lane];
            b1l = ebl[(ct + 1) * 128 + 64 + lane];
        }
        floatx4 a0 = {0.f, 0.f, 0.f, 0.f};
        floatx4 a1 = {0.f, 0.f, 0.f, 0.f};
        // S = xh*eh + xh*el + xl*eh, fp32 accumulate
        a0 = __builtin_amdgcn_mfma_f32_16x16x32_bf16(ah[0][0], ch0, a0, 0, 0, 0);
        a0 = __builtin_amdgcn_mfma_f32_16x16x32_bf16(ah[0][1], ch1, a0, 0, 0, 0);
        a0 = __builtin_amdgcn_mfma_f32_16x16x32_bf16(ah[0][0], cB0, a0, 0, 0, 0);
        a0 = __builtin_amdgcn_mfma_f32_16x16x32_bf16(ah[0][1], cB1, a0, 0, 0, 0);
        a0 = __builtin_amdgcn_mfma_f32_16x16x32_bf16(al[0][0], ch0, a0, 0, 0, 0);
        a0 = __builtin_amdgcn_mfma_f32_16x16x32_bf16(al[0][1], ch1, a0, 0, 0, 0);
        a1 = __builtin_amdgcn_mfma_f32_16x16x32_bf16(ah[1][0], ch0, a1, 0, 0, 0);
        a1 = __builtin_amdgcn_mfma_f32_16x16x32_bf16(ah[1][1], ch1, a1, 0, 0, 0);
        a1 = __builtin_amdgcn_mfma_f32_16x16x32_bf16(ah[1][0], cB0, a1, 0, 0, 0);
        a1 = __builtin_amdgcn_mfma_f32_16x16x32_bf16(ah[1][1], cB1, a1, 0, 0, 0);
        a1 = __builtin_amdgcn_mfma_f32_16x16x32_bf16(al[1][0], ch0, a1, 0, 0, 0);
        a1 = __builtin_amdgcn_mfma_f32_16x16x32_bf16(al[1][1], ch1, a1, 0, 0, 0);

        const float sel = se[ct * 16 + cl];
        const int  code = ct * 16 + cl;
#pragma unroll
        for (int r = 0; r < 4; ++r) {
            float d0 = fmaf(-2.f, a0[r], sel);
            if (d0 < minv[0][r]) { minv[0][r] = d0; mini[0][r] = code; }
            float d1 = fmaf(-2.f, a1[r], sel);
            if (d1 < minv[1][r]) { minv[1][r] = d1; mini[1][r] = code; }
        }
    }

    // ---- Phase C: reduce (val,idx) across 16 lanes; write idx/hist/loss and
    //      scatter the one-hot 1.0 (enc region was pre-zeroed by initzero).
    float lossp = 0.f;
#pragma unroll
    for (int s = 0; s < 2; ++s)
#pragma unroll
        for (int r = 0; r < 4; ++r) {
            float v = minv[s][r]; int i = mini[s][r];
#pragma unroll
            for (int m = 1; m <= 8; m <<= 1) {
                float ov = __shfl_xor(v, m, 64);
                int   oi = __shfl_xor(i, m, 64);
                if (ov < v || (ov == v && oi < i)) { v = ov; i = oi; }
            }
            if ((lane & 15) == 0) {
                int row_loc = wid * 32 + s * 16 + (lane >> 4) * 4 + r;
                int row = rblk + row_loc;
                idxout[row] = i;
                atomicAdd(&hist[i], 1);
                lossp += v;                     // d'_min for this row
                enc[((size_t)row << 10) + i] = 1.0f;
            }
        }
#pragma unroll
    for (int m = 1; m <= 32; m <<= 1) lossp += __shfl_xor(lossp, m, 64);
    if (lane == 0) atomicAdd(lossacc, lossp);
}

// ---- quantized NCHW gather, LDS-tiled for coalesced writes (proven R5) ----
__global__ __launch_bounds__(256) void vq_qout_kernel(
    const float4* __restrict__ emb4, const int* __restrict__ idx,
    float* __restrict__ outq)
{
    __shared__ float q[64 * 65];
    __shared__ int ks[64];
    const int tid = threadIdx.x;
    const int n   = blockIdx.x >> 4;
    const int hw0 = (blockIdx.x & 15) << 6;
    if (tid < 64) ks[tid] = idx[(n << 10) + hw0 + tid];
    __syncthreads();
#pragma unroll
    for (int i = 0; i < 4; ++i) {
        int flat = tid + (i << 8);        // 0..1023 = 64 rows x 16 float4
        int hw = flat >> 4;
        int f4 = flat & 15;
        float4 v = emb4[(ks[hw] << 4) + f4];   // 256 B row reads, L2-hot
        float* dst = &q[hw * 65 + (f4 << 2)];
        dst[0] = v.x; dst[1] = v.y; dst[2] = v.z; dst[3] = v.w;
    }
    __syncthreads();
    const int lane_hw = tid & 63;
    const int cw = tid >> 6;              // wave id 0..3 -> c block
    float* ob = outq + ((size_t)n << 16) + hw0 + lane_hw;
#pragma unroll
    for (int j = 0; j < 16; ++j) {
        int c = cw * 16 + j;
        __builtin_nontemporal_store(q[lane_hw * 65 + c], &ob[(size_t)c << 10]);
    }
}

__global__ __launch_bounds__(256) void vq_final_kernel(
    const int* __restrict__ hist, const float* __restrict__ lossacc,
    const float* __restrict__ sumx2, float* __restrict__ out)
{
    const int tid = threadIdx.x;
    float s = 0.f;
    for (int k = tid; k < KCB; k += 256) {
        float p = (float)hist[k] * (1.f / 65536.f);
        s += p * logf(p + 1e-10f);
    }
    __shared__ float red[256];
    red[tid] = s;
    __syncthreads();
    for (int st = 128; st > 0; st >>= 1) {
        if (tid < st) red[tid] += red[tid + st];
        __syncthreads();
    }
    if (tid == 0) {
        // mean||x-q||^2 = (sum x^2 + sum d'_min) / numel
        out[0] = 0.25f * (sumx2[0] + lossacc[0]) * (1.f / 4194304.f);
        out[4194305] = expf(-red[0]);
    }
}

extern "C" void kernel_launch(void* const* d_in, const int* in_sizes, int n_in,
                              void* d_out, int out_size, void* d_ws, size_t ws_size,
                              hipStream_t stream) {
    const float* inp = (const float*)d_in[0];
    const float* emb = (const float*)d_in[1];
    float* out = (float*)d_out;

    float* wsf     = (float*)d_ws;
    float* se      = wsf;                     // 1024 f
    int*   hist    = (int*)(wsf + 1024);      // 1024 i
    float* lossacc = wsf + 2048;              // sum d'_min
    float* sumx2   = wsf + 2049;              // sum x^2
    int*   idx     = (int*)(wsf + 2304);      // 65536 i

    float* outq = out + 1;
    float* enc  = out + 4194306;              // 67,108,864 f (256 MB)

    // B-frags parked in the QUANTIZED region of d_out (dead until vq_qout,
    // which runs after mega). Each array is 32768 floats = 128 KB. out+4 is
    // 16 B aligned.
    short8* ebh = (short8*)(out + 4);             // 128 KB
    short8* ebl = (short8*)(out + 4 + 32768);     // 128 KB

    vq_initzero_kernel<<<2048, 256, 0, stream>>>(emb, se, hist, lossacc, sumx2,
                                                 ebh, ebl, enc);
    vq_mega_kernel <<<512,  256, 0, stream>>>(inp, ebh, ebl, se, idx, hist,
                                              lossacc, sumx2, enc);
    vq_qout_kernel <<<1024, 256, 0, stream>>>((const float4*)emb, idx, outq);
    vq_final_kernel<<<1,    256, 0, stream>>>(hist, lossacc, sumx2, out);
}

// Round 2
// 378.997 us; speedup vs baseline: 1.0867x; 1.0867x over previous
//
#include <hip/hip_runtime.h>

// VQ-VAE eval forward, MI355X — R9: revert to the R7 fused structure (R8's
// split zero-fill serialized a write that was already overlapped: 381.7 ->
// 411.9). On top of R7:
//   (a) Phase D enc writes widened to float4: each wave owns a contiguous
//       128 KB (32 rows); per 4-KB row = head floatx2 + 255 aligned float4 +
//       tail floatx2 (enc base is only 8-B aligned: out + 4194306 floats).
//       One-hot component selected branchlessly per float4.
//   (b) hist pre-aggregated in LDS (LDS atomics), flushed as <=128 global
//       atomics per block — removes device-atomic same-line serialization in
//       the concentrated-argmin case.
// inputs:  d_in[0] = inputs  fp32 [64,64,32,32] NCHW  (4,194,304)
//          d_in[1] = emb     fp32 [1024,64]           (65,536)
// outputs in d_out (fp32, flat): loss | quantized NCHW (4194304) |
//          perplexity | encodings [65536,1024] (256 MB)

#define NROWS 65536
#define DIM   64
#define KCB   1024

typedef __attribute__((ext_vector_type(8))) short  short8;
typedef __attribute__((ext_vector_type(4))) float  floatx4;
typedef __attribute__((ext_vector_type(2))) float  floatx2;

__device__ inline unsigned short f2bf(float f) {
    unsigned u = __float_as_uint(f);
    u = u + 0x7fffu + ((u >> 16) & 1u);      // round-to-nearest-even
    return (unsigned short)(u >> 16);
}
__device__ inline float bf2f(unsigned short h) {
    return __uint_as_float(((unsigned)h) << 16);
}

// ---- init: se[k], hist=0, scalars=0, e -> B-fragment-ordered bf16 hi/lo ----
// B-frag layout (16x16x32): elem (ct,kt,lane,j) = emb[code=ct*16+(lane&15)]
//                           [dim=kt*32+(lane>>4)*8+j]
__global__ __launch_bounds__(256) void vq_init_kernel(
    const float* __restrict__ emb, float* __restrict__ se,
    int* __restrict__ hist, float* __restrict__ lossacc, float* __restrict__ sumx2,
    short8* __restrict__ ebh, short8* __restrict__ ebl)
{
    const int code = blockIdx.x * 256 + threadIdx.x;   // 0..1023
    const float* e = emb + (code << 6);
    float s = 0.f;
    float v[DIM];
#pragma unroll
    for (int d = 0; d < DIM; ++d) { v[d] = e[d]; s = fmaf(v[d], v[d], s); }
    se[code] = s;
    hist[code] = 0;
    if (code == 0) { lossacc[0] = 0.f; sumx2[0] = 0.f; }

    const int ct = code >> 4;
#pragma unroll
    for (int jg = 0; jg < 8; ++jg) {                   // dims jg*8 .. jg*8+7
        const int kt   = jg >> 2;
        const int lane = (code & 15) + 16 * (jg & 3);
        short8 h8, l8;
#pragma unroll
        for (int j = 0; j < 8; ++j) {
            float x = v[jg * 8 + j];
            unsigned short h = f2bf(x);
            h8[j] = (short)h;
            l8[j] = (short)f2bf(x - bf2f(h));
        }
        ebh[(ct * 2 + kt) * 64 + lane] = h8;
        ebl[(ct * 2 + kt) * 64 + lane] = l8;
    }
}

// ---- mega: block = 128 rows. Phase A: x load + bf16-split -> LDS A-frags.
//      Phase B: MFMA argmin over all 1024 codes (B-frags double-buffered from
//      global). Phase C: idx / LDS-hist / loss. Phase D: hist flush + per-wave
//      float4 enc-row streaming.
__global__ __launch_bounds__(256) void vq_mega_kernel(
    const float* __restrict__ inp, const short8* __restrict__ ebh,
    const short8* __restrict__ ebl, const float* __restrict__ se,
    int* __restrict__ idxout, int* __restrict__ hist,
    float* __restrict__ lossacc, float* __restrict__ sumx2,
    float* __restrict__ enc)
{
    __shared__ short8 fragH[1024];   // [s16_loc(8)][kt(2)][lane(64)], 16 KB
    __shared__ short8 fragL[1024];   // 16 KB
    __shared__ int ks[128];
    __shared__ int hist_l[KCB];      // 4 KB per-block histogram

    const int tid  = threadIdx.x;
    const int rblk = blockIdx.x << 7;        // first row of this block
    const int n    = rblk >> 10;             // 128 | 1024 -> single n per block
    const int hw0  = rblk & 1023;

#pragma unroll
    for (int i = 0; i < 4; ++i) hist_l[tid + (i << 8)] = 0;

    // ---- Phase A ----
    {
        const int r_loc = tid & 127;
        const int half  = tid >> 7;          // dims half*32 .. +31
        const float* base = inp + n * 65536 + hw0 + r_loc;
        float v[32];
        float s2 = 0.f;
#pragma unroll
        for (int j = 0; j < 32; ++j) {
            v[j] = base[(half * 32 + j) << 10];   // 256 B coalesced per instr
            s2 = fmaf(v[j], v[j], s2);
        }
        const int s16 = r_loc >> 4;
#pragma unroll
        for (int jg2 = 0; jg2 < 4; ++jg2) {       // jg = half*4 + jg2
            short8 h8, l8;
#pragma unroll
            for (int jj = 0; jj < 8; ++jj) {
                float x = v[jg2 * 8 + jj];
                unsigned short h = f2bf(x);
                h8[jj] = (short)h;
                l8[jj] = (short)f2bf(x - bf2f(h));
            }
            // kt = jg>>2 = half; lane = (row&15) + 16*(jg&3), jg&3 = jg2
            int fi = (s16 * 2 + half) * 64 + (r_loc & 15) + (jg2 << 4);
            fragH[fi] = h8;
            fragL[fi] = l8;
        }
#pragma unroll
        for (int m = 1; m <= 32; m <<= 1) s2 += __shfl_xor(s2, m, 64);
        if ((tid & 63) == 0) atomicAdd(sumx2, s2);
    }
    __syncthreads();

    // ---- Phase B: MFMA argmin ----
    const int lane = tid & 63;
    const int wid  = tid >> 6;

    short8 ah[2][2], al[2][2];
#pragma unroll
    for (int s = 0; s < 2; ++s)
#pragma unroll
        for (int kt = 0; kt < 2; ++kt) {
            int fi = ((wid * 2 + s) * 2 + kt) * 64 + lane;
            ah[s][kt] = fragH[fi];
            al[s][kt] = fragL[fi];
        }

    float minv[2][4]; int mini[2][4];
#pragma unroll
    for (int s = 0; s < 2; ++s)
#pragma unroll
        for (int r = 0; r < 4; ++r) { minv[s][r] = 3.0e38f; mini[s][r] = 0; }

    const int cl = lane & 15;
    short8 b0h = ebh[lane], b0l = ebl[lane];
    short8 b1h = ebh[64 + lane], b1l = ebl[64 + lane];

    for (int ct = 0; ct < 64; ++ct) {
        short8 ch0 = b0h, cB0 = b0l, ch1 = b1h, cB1 = b1l;
        if (ct < 63) {                         // double-buffer next B-frags
            b0h = ebh[(ct + 1) * 128 + lane];
            b0l = ebl[(ct + 1) * 128 + lane];
            b1h = ebh[(ct + 1) * 128 + 64 + lane];
            b1l = ebl[(ct + 1) * 128 + 64 + lane];
        }
        floatx4 a0 = {0.f, 0.f, 0.f, 0.f};
        floatx4 a1 = {0.f, 0.f, 0.f, 0.f};
        // S = xh*eh + xh*el + xl*eh, fp32 accumulate
        a0 = __builtin_amdgcn_mfma_f32_16x16x32_bf16(ah[0][0], ch0, a0, 0, 0, 0);
        a0 = __builtin_amdgcn_mfma_f32_16x16x32_bf16(ah[0][1], ch1, a0, 0, 0, 0);
        a0 = __builtin_amdgcn_mfma_f32_16x16x32_bf16(ah[0][0], cB0, a0, 0, 0, 0);
        a0 = __builtin_amdgcn_mfma_f32_16x16x32_bf16(ah[0][1], cB1, a0, 0, 0, 0);
        a0 = __builtin_amdgcn_mfma_f32_16x16x32_bf16(al[0][0], ch0, a0, 0, 0, 0);
        a0 = __builtin_amdgcn_mfma_f32_16x16x32_bf16(al[0][1], ch1, a0, 0, 0, 0);
        a1 = __builtin_amdgcn_mfma_f32_16x16x32_bf16(ah[1][0], ch0, a1, 0, 0, 0);
        a1 = __builtin_amdgcn_mfma_f32_16x16x32_bf16(ah[1][1], ch1, a1, 0, 0, 0);
        a1 = __builtin_amdgcn_mfma_f32_16x16x32_bf16(ah[1][0], cB0, a1, 0, 0, 0);
        a1 = __builtin_amdgcn_mfma_f32_16x16x32_bf16(ah[1][1], cB1, a1, 0, 0, 0);
        a1 = __builtin_amdgcn_mfma_f32_16x16x32_bf16(al[1][0], ch0, a1, 0, 0, 0);
        a1 = __builtin_amdgcn_mfma_f32_16x16x32_bf16(al[1][1], ch1, a1, 0, 0, 0);

        const float sel = se[ct * 16 + cl];
        const int  code = ct * 16 + cl;
#pragma unroll
        for (int r = 0; r < 4; ++r) {
            float d0 = fmaf(-2.f, a0[r], sel);
            if (d0 < minv[0][r]) { minv[0][r] = d0; mini[0][r] = code; }
            float d1 = fmaf(-2.f, a1[r], sel);
            if (d1 < minv[1][r]) { minv[1][r] = d1; mini[1][r] = code; }
        }
    }

    // ---- Phase C: reduce (val,idx) across 16 lanes; write idx/ks/loss and
    //      accumulate the block histogram in LDS (cheap atomics).
    float lossp = 0.f;
#pragma unroll
    for (int s = 0; s < 2; ++s)
#pragma unroll
        for (int r = 0; r < 4; ++r) {
            float v = minv[s][r]; int i = mini[s][r];
#pragma unroll
            for (int m = 1; m <= 8; m <<= 1) {
                float ov = __shfl_xor(v, m, 64);
                int   oi = __shfl_xor(i, m, 64);
                if (ov < v || (ov == v && oi < i)) { v = ov; i = oi; }
            }
            if ((lane & 15) == 0) {
                int row_loc = wid * 32 + s * 16 + (lane >> 4) * 4 + r;
                idxout[rblk + row_loc] = i;
                ks[row_loc] = i;
                atomicAdd(&hist_l[i], 1);
                lossp += v;                     // d'_min for this row
            }
        }
#pragma unroll
    for (int m = 1; m <= 32; m <<= 1) lossp += __shfl_xor(lossp, m, 64);
    if (lane == 0) atomicAdd(lossacc, lossp);
    __syncthreads();

    // ---- hist flush: <=128 nonzero bins per block -> global atomics ----
#pragma unroll
    for (int i = 0; i < 4; ++i) {
        int b = tid + (i << 8);
        int c = hist_l[b];
        if (c) atomicAdd(&hist[b], c);
    }

    // ---- Phase D: enc rows, float4-wide. Wave owns rows [wid*32, +32) =
    //      contiguous 128 KB. Row byte base ≡ 8 (mod 16): head f2 (floats
    //      0-1), 255 aligned float4 (floats 2..1021), tail f2 (1022-1023).
#pragma unroll 2
    for (int rr = 0; rr < 32; ++rr) {
        const int row_loc = wid * 32 + rr;
        const int k = ks[row_loc];
        float* rowp = enc + ((size_t)(rblk + row_loc) << 10);
        floatx4* p4 = (floatx4*)(rowp + 2);    // 16-B aligned
#pragma unroll
        for (int i = 0; i < 4; ++i) {
            int j = (i << 6) + lane;           // float4 index 0..255
            if (j < 255) {
                int f0 = (j << 2) + 2;         // first float covered
                floatx4 zv;
                zv[0] = (k == f0    ) ? 1.f : 0.f;
                zv[1] = (k == f0 + 1) ? 1.f : 0.f;
                zv[2] = (k == f0 + 2) ? 1.f : 0.f;
                zv[3] = (k == f0 + 3) ? 1.f : 0.f;
                __builtin_nontemporal_store(zv, &p4[j]);
            } else if (j == 255) {             // lane 63 @ i=3: head + tail
                floatx2 h, t;
                h[0] = (k == 0   ) ? 1.f : 0.f;
                h[1] = (k == 1   ) ? 1.f : 0.f;
                t[0] = (k == 1022) ? 1.f : 0.f;
                t[1] = (k == 1023) ? 1.f : 0.f;
                __builtin_nontemporal_store(h, (floatx2*)rowp);
                __builtin_nontemporal_store(t, (floatx2*)(rowp + 1022));
            }
        }
    }
}

// ---- quantized NCHW gather, LDS-tiled for coalesced writes (proven R5) ----
__global__ __launch_bounds__(256) void vq_qout_kernel(
    const float4* __restrict__ emb4, const int* __restrict__ idx,
    float* __restrict__ outq)
{
    __shared__ float q[64 * 65];
    __shared__ int ks[64];
    const int tid = threadIdx.x;
    const int n   = blockIdx.x >> 4;
    const int hw0 = (blockIdx.x & 15) << 6;
    if (tid < 64) ks[tid] = idx[(n << 10) + hw0 + tid];
    __syncthreads();
#pragma unroll
    for (int i = 0; i < 4; ++i) {
        int flat = tid + (i << 8);        // 0..1023 = 64 rows x 16 float4
        int hw = flat >> 4;
        int f4 = flat & 15;
        float4 v = emb4[(ks[hw] << 4) + f4];   // 256 B row reads, L2-hot
        float* dst = &q[hw * 65 + (f4 << 2)];
        dst[0] = v.x; dst[1] = v.y; dst[2] = v.z; dst[3] = v.w;
    }
    __syncthreads();
    const int lane_hw = tid & 63;
    const int cw = tid >> 6;              // wave id 0..3 -> c block
    float* ob = outq + ((size_t)n << 16) + hw0 + lane_hw;
#pragma unroll
    for (int j = 0; j < 16; ++j) {
        int c = cw * 16 + j;
        __builtin_nontemporal_store(q[lane_hw * 65 + c], &ob[(size_t)c << 10]);
    }
}

__global__ __launch_bounds__(256) void vq_final_kernel(
    const int* __restrict__ hist, const float* __restrict__ lossacc,
    const float* __restrict__ sumx2, float* __restrict__ out)
{
    const int tid = threadIdx.x;
    float s = 0.f;
    for (int k = tid; k < KCB; k += 256) {
        float p = (float)hist[k] * (1.f / 65536.f);
        s += p * logf(p + 1e-10f);
    }
    __shared__ float red[256];
    red[tid] = s;
    __syncthreads();
    for (int st = 128; st > 0; st >>= 1) {
        if (tid < st) red[tid] += red[tid + st];
        __syncthreads();
    }
    if (tid == 0) {
        // mean||x-q||^2 = (sum x^2 + sum d'_min) / numel
        out[0] = 0.25f * (sumx2[0] + lossacc[0]) * (1.f / 4194304.f);
        out[4194305] = expf(-red[0]);
    }
}

extern "C" void kernel_launch(void* const* d_in, const int* in_sizes, int n_in,
                              void* d_out, int out_size, void* d_ws, size_t ws_size,
                              hipStream_t stream) {
    const float* inp = (const float*)d_in[0];
    const float* emb = (const float*)d_in[1];
    float* out = (float*)d_out;

    float* wsf     = (float*)d_ws;
    float* se      = wsf;                     // 1024 f
    int*   hist    = (int*)(wsf + 1024);      // 1024 i
    float* lossacc = wsf + 2048;              // sum d'_min
    float* sumx2   = wsf + 2049;              // sum x^2
    int*   idx     = (int*)(wsf + 2304);      // 65536 i

    float* outq = out + 1;
    float* enc  = out + 4194306;              // 67,108,864 f (256 MB)

    // B-frags parked in the QUANTIZED region of d_out (dead until vq_qout,
    // which runs after mega). Each array is 32768 floats = 128 KB. out+4 is
    // 16 B aligned.
    short8* ebh = (short8*)(out + 4);             // 128 KB
    short8* ebl = (short8*)(out + 4 + 32768);     // 128 KB

    vq_init_kernel <<<4,    256, 0, stream>>>(emb, se, hist, lossacc, sumx2, ebh, ebl);
    vq_mega_kernel <<<512,  256, 0, stream>>>(inp, ebh, ebl, se, idx, hist,
                                              lossacc, sumx2, enc);
    vq_qout_kernel <<<1024, 256, 0, stream>>>((const float4*)emb, idx, outq);
    vq_final_kernel<<<1,    256, 0, stream>>>(hist, lossacc, sumx2, out);
}